// Round 1
// 230.010 us; speedup vs baseline: 1.0341x; 1.0341x over previous
//
#include <hip/hip_runtime.h>
#include <cstdint>

typedef __attribute__((ext_vector_type(8))) short bf16x8;
typedef __attribute__((ext_vector_type(4))) float f32x4;

#define B_   4
#define C_   128
#define H_   128
#define W_   128
#define HP_  130
#define WP_  130
#define O_   256
#define HW_  (H_*W_)          // 16384

// ws layout (byte offsets)
#define XPAD_BYTES   (B_*HP_*WP_*C_*2)          // bf16 xpad: 17,305,600
#define OFF_BYTE     XPAD_BYTES
#define OFF_BYTES    (B_*HW_*18*4)              // 4,718,592
#define WREPB_BYTE   (OFF_BYTE + OFF_BYTES)
#define WREPB_BYTES  (9*C_*O_*2)                // 589,824
#define STATS_BYTE   (WREPB_BYTE + WREPB_BYTES)
#define WOFF_BYTE    (STATS_BYTE + 4096)
#define WOFF_BYTES   (9*4*4*32*8*2)             // 73,728

typedef __attribute__((address_space(1))) const void gconst_void;
typedef __attribute__((address_space(3))) void lds_void;
#define GLD_LDS16(gp, lp) __builtin_amdgcn_global_load_lds((gconst_void*)(gp), (lds_void*)(lp), 16, 0, 0)

__device__ __forceinline__ unsigned pack_bf2(float a, float b) {
    unsigned ua = __builtin_bit_cast(unsigned, a) + 0x8000u;
    unsigned ub = __builtin_bit_cast(unsigned, b) + 0x8000u;
    return __builtin_amdgcn_perm(ub, ua, 0x07060302u);
}

// ---------------- K1: NCHW fp32 -> padded NHWC bf16 transpose ----------------
__global__ void k_transpose(const float* __restrict__ x, unsigned short* __restrict__ xpad) {
    __shared__ float tile[32][33];   // [c_loc][w_loc]
    int w0 = blockIdx.x * 32, c0 = blockIdx.y * 32;
    int bh = blockIdx.z;
    int b = bh >> 7, h = bh & 127;
    int tx = threadIdx.x, ty = threadIdx.y;
#pragma unroll
    for (int i = 0; i < 4; i++) {
        int c = c0 + ty + i * 8;
        tile[ty + i * 8][tx] = x[((b * C_ + c) * H_ + h) * W_ + w0 + tx];
    }
    __syncthreads();
    int tid = ty * 32 + tx;
    int cp = tid & 15;
    int wl = tid >> 4;
#pragma unroll
    for (int i = 0; i < 2; i++) {
        int wll = wl + i * 16;
        int w = w0 + wll;
        unsigned v = pack_bf2(tile[2 * cp][wll], tile[2 * cp + 1][wll]);
        *(unsigned*)(&xpad[((size_t)((b * HP_ + h + 1) * WP_ + (w + 1))) * C_ + c0 + 2 * cp]) = v;
    }
}

// ---------------- K2a: repack p_w -> bf16 A-fragments [tap][kc][q][m32][e8], m>=18 zero ----------------
__global__ void k_repack2(const float* __restrict__ p_w, short* __restrict__ wofff) {
    int i = blockIdx.x * 256 + threadIdx.x;
    if (i < 9 * 4096) {
        int e = i & 7, m = (i >> 3) & 31, q = (i >> 8) & 3, kc = (i >> 10) & 3, tap = i >> 12;
        float f = (m < 18) ? p_w[((size_t)m * C_ + kc * 32 + q * 8 + e) * 9 + tap] : 0.f;
        unsigned u = __builtin_bit_cast(unsigned, f);
        u += 0x7fffu + ((u >> 16) & 1u);   // RNE
        wofff[i] = (short)(u >> 16);
    }
}

// ---------------- K2: offset conv as MFMA GEMM (M=18 pad 32, K=1152) ----------------
__global__ __launch_bounds__(256) void k_offconv(const unsigned short* __restrict__ xpad,
                                                 const short* __restrict__ wofff,
                                                 const float* __restrict__ p_b,
                                                 float* __restrict__ offT) {
    int t = threadIdx.x;
    int ph = blockIdx.x;
    int h  = blockIdx.y;
    int b  = blockIdx.z;
    const unsigned short* xb = xpad + (size_t)b * HP_ * WP_ * C_;
    int lane = t & 63, wv = t >> 6;
    int q = lane >> 4, l15 = lane & 15;
    int pos0 = ph * 64 + wv * 16;
    int poscol = pos0 + l15;

    f32x4 accA = {0.f, 0.f, 0.f, 0.f}, accB = {0.f, 0.f, 0.f, 0.f};
    const bf16x8* Wf = (const bf16x8*)wofff;

    for (int tap = 0; tap < 9; tap++) {
        int row = h + tap / 3;
        int col = poscol + tap % 3;
        const unsigned short* src = xb + ((size_t)(row * WP_ + col)) * C_ + q * 8;
#pragma unroll
        for (int kc = 0; kc < 4; kc++) {
            bf16x8 a0 = Wf[(size_t)(((tap * 4 + kc) * 4 + q) * 32) + l15];
            bf16x8 a1 = Wf[(size_t)(((tap * 4 + kc) * 4 + q) * 32) + 16 + l15];
            bf16x8 bv = *(const bf16x8*)(src + kc * 32);
            accA = __builtin_amdgcn_mfma_f32_16x16x32_bf16(a0, bv, accA, 0, 0, 0);
            accB = __builtin_amdgcn_mfma_f32_16x16x32_bf16(a1, bv, accB, 0, 0, 0);
        }
    }
    size_t hw = (size_t)h * W_ + pos0 + l15;
#pragma unroll
    for (int r = 0; r < 4; r++) {
        int j = q * 4 + r;
        offT[((size_t)(b * 18 + j)) * HW_ + hw] = accA[r] + p_b[j];
    }
    if (q == 0) {
#pragma unroll
        for (int r = 0; r < 2; r++) {
            int j = 16 + r;
            offT[((size_t)(b * 18 + j)) * HW_ + hw] = accB[r] + p_b[j];
        }
    }
}

// ---------------- K2b: repack w_conv -> bf16 [n][kc4][kq4][o256][ki8] ----------------
__global__ void k_repack(const float* __restrict__ w_conv, unsigned short* __restrict__ wrepb) {
    int i = blockIdx.x * 256 + threadIdx.x;
    if (i < 9 * C_ * O_) {
        int ki8 = i & 7;
        int o   = (i >> 3) & 255;
        int kq  = (i >> 11) & 3;
        int kc  = (i >> 13) & 3;
        int n   = i >> 15;
        int c = kc * 32 + kq * 8 + ki8;
        float f = w_conv[(o * C_ + c) * 9 + n];
        unsigned u = __builtin_bit_cast(unsigned, f);
        u += 0x7fffu + ((u >> 16) & 1u);   // RNE
        wrepb[i] = (unsigned short)(u >> 16);
    }
}

// ---------------- K3: one block per (b,h); software-pipelined: issue loads(s+1) -> MFMA(s) -> blend/write(s+1) -> 1 barrier ----------------
__global__ __launch_bounds__(512, 4) void k_main(const unsigned short* __restrict__ xpad,
                                                 const float* __restrict__ offT,
                                                 const unsigned short* __restrict__ wrepb,
                                                 float* __restrict__ out,
                                                 float* __restrict__ stats) {
    __shared__ short Wl[2][8192];        // double-buffered W chunk, 32 KB
    __shared__ short Vl[2][4128];        // double-buffered skewed V, 16.5 KB
    __shared__ int   pbase[2][4][128];   // tap-parity double buffer, 4 KB
    __shared__ float pg[2][4][128];      // 4 KB
    __shared__ float red0[256], red1[256];

    int t = threadIdx.x;
    int i_blk = blockIdx.x;
    int b = i_blk & 3;                   // XCD k serves b = k&3 only (round-robin heuristic)
    int h = i_blk >> 2;
    const unsigned short* xb = xpad + (size_t)b * HP_ * WP_ * C_;

    int lane = t & 63, wv = t >> 6;      // 8 waves
    int q = lane >> 4, l15 = lane & 15;
    int m0 = (wv & 3) * 64;              // o-slice
    int ph = wv >> 2;                    // pos half
    int n0 = ph * 64;
    int c4g = t & 3, posb = t >> 2;      // gather: 4 ch-subquads x 128 pos

    auto OFFSETS = [&](int n, int pb) {
        if (t < 128) {
            int w = t;
            float offx = offT[((size_t)(b * 18 + n)) * HW_ + h * W_ + w];
            float offy = offT[((size_t)(b * 18 + 9 + n)) * HW_ + h * W_ + w];
            int dxn = n / 3 - 1, dyn = n % 3 - 1;
            float px = (float)(h + 1 + dxn) + offx;
            float py = (float)(w + 1 + dyn) + offy;
            float pcx = fminf(fmaxf(px, 0.f), 129.f);
            float pcy = fminf(fmaxf(py, 0.f), 129.f);
            float fx = floorf(px), fy = floorf(py);
            float q0x = fminf(fmaxf(fx, 0.f), 129.f);
            float q0y = fminf(fmaxf(fy, 0.f), 129.f);
            float q1x = fminf(fmaxf(fx + 1.f, 0.f), 129.f);
            float q1y = fminf(fmaxf(fy + 1.f, 0.f), 129.f);
            float wx0 = 1.f + (q0x - pcx), wx1 = 1.f - (q1x - pcx);
            float wy0 = 1.f + (q0y - pcy), wy1 = 1.f - (q1y - pcy);
            int i0x = (int)q0x, i0y = (int)q0y, i1x = (int)q1x, i1y = (int)q1y;
            pbase[pb][0][w] = (i0x * WP_ + i0y) * C_;
            pbase[pb][1][w] = (i1x * WP_ + i1y) * C_;
            pbase[pb][2][w] = (i0x * WP_ + i1y) * C_;
            pbase[pb][3][w] = (i1x * WP_ + i0y) * C_;
            pg[pb][0][w] = wx0 * wy0;
            pg[pb][1][w] = wx1 * wy1;
            pg[pb][2][w] = wx0 * wy1;
            pg[pb][3][w] = wx1 * wy0;
        }
    };

    f32x4 acc[4][4];
#pragma unroll
    for (int i = 0; i < 4; i++)
#pragma unroll
        for (int j = 0; j < 4; j++) acc[i][j] = (f32x4){0.f, 0.f, 0.f, 0.f};

    OFFSETS(0, 0);
    __syncthreads();

    // ---- prologue: stage step 0 into buffer 0 ----
    {
        const unsigned short* ws = wrepb;            // chunk 0
        GLD_LDS16(ws + (size_t)t * 8, &Wl[0][wv * 512]);
        GLD_LDS16(ws + (size_t)(t + 512) * 8, &Wl[0][wv * 512 + 4096]);
        int cof = c4g * 8;                           // kc=0
        uint4 A  = *(const uint4*)(xb + pbase[0][0][posb] + cof);
        uint4 Bv = *(const uint4*)(xb + pbase[0][1][posb] + cof);
        uint4 Cv = *(const uint4*)(xb + pbase[0][2][posb] + cof);
        uint4 Dv = *(const uint4*)(xb + pbase[0][3][posb] + cof);
        float g0 = pg[0][0][posb], g1 = pg[0][1][posb], g2 = pg[0][2][posb], g3 = pg[0][3][posb];
        unsigned outw[4];
#pragma unroll
        for (int k = 0; k < 4; k++) {
            unsigned ua = (&A.x)[k], ub = (&Bv.x)[k], uc = (&Cv.x)[k], ud = (&Dv.x)[k];
            float alo = __builtin_bit_cast(float, ua << 16), ahi = __builtin_bit_cast(float, ua & 0xffff0000u);
            float blo = __builtin_bit_cast(float, ub << 16), bhi = __builtin_bit_cast(float, ub & 0xffff0000u);
            float clo = __builtin_bit_cast(float, uc << 16), chi = __builtin_bit_cast(float, uc & 0xffff0000u);
            float dlo = __builtin_bit_cast(float, ud << 16), dhi = __builtin_bit_cast(float, ud & 0xffff0000u);
            float vlo = g0 * alo + g1 * blo + g2 * clo + g3 * dlo;
            float vhi = g0 * ahi + g1 * bhi + g2 * chi + g3 * dhi;
            outw[k] = pack_bf2(vlo, vhi);
        }
        *(uint4*)&Vl[0][(unsigned)(c4g * 129 + posb) * 8] = make_uint4(outw[0], outw[1], outw[2], outw[3]);
    }
    __syncthreads();

    // ---- main pipelined loop: 36 steps, 1 barrier per step ----
#pragma unroll 1
    for (int s = 0; s < 36; s++) {
        int cur = s & 1, nxt = cur ^ 1;
        uint4 A, Bv, Cv, Dv;
        float g0 = 0.f, g1 = 0.f, g2 = 0.f, g3 = 0.f;
        bool st = (s < 35);
        if (st) {
            int s1 = s + 1;
            const unsigned short* ws = wrepb + (size_t)s1 * 8192;
            GLD_LDS16(ws + (size_t)t * 8, &Wl[nxt][wv * 512]);
            GLD_LDS16(ws + (size_t)(t + 512) * 8, &Wl[nxt][wv * 512 + 4096]);
            int n1 = s1 >> 2, kc1 = s1 & 3, pb1 = n1 & 1;
            int cof = kc1 * 32 + c4g * 8;
            A  = *(const uint4*)(xb + pbase[pb1][0][posb] + cof);
            Bv = *(const uint4*)(xb + pbase[pb1][1][posb] + cof);
            Cv = *(const uint4*)(xb + pbase[pb1][2][posb] + cof);
            Dv = *(const uint4*)(xb + pbase[pb1][3][posb] + cof);
            g0 = pg[pb1][0][posb]; g1 = pg[pb1][1][posb];
            g2 = pg[pb1][2][posb]; g3 = pg[pb1][3][posb];
        }
        // consume step s: loads for s+1 are in flight underneath the MFMAs
        {
            const bf16x8* Af = (const bf16x8*)Wl[cur];
            const bf16x8* Bf = (const bf16x8*)Vl[cur];
            bf16x8 av[4];
#pragma unroll
            for (int i = 0; i < 4; i++) av[i] = Af[q * 256 + m0 + i * 16 + l15];
            __builtin_amdgcn_s_setprio(1);
#pragma unroll
            for (int j = 0; j < 4; j++) {
                bf16x8 bv = Bf[q * 129 + n0 + j * 16 + l15];
#pragma unroll
                for (int i = 0; i < 4; i++)
                    acc[i][j] = __builtin_amdgcn_mfma_f32_16x16x32_bf16(av[i], bv, acc[i][j], 0, 0, 0);
            }
            __builtin_amdgcn_s_setprio(0);
        }
        // compute offsets one tap ahead (off the critical path, disjoint pb buffer)
        if ((s & 3) == 2) {
            int n = s >> 2;
            if (n < 8) OFFSETS(n + 1, (n + 1) & 1);
        }
        if (st) {
            unsigned outw[4];
#pragma unroll
            for (int k = 0; k < 4; k++) {
                unsigned ua = (&A.x)[k], ub = (&Bv.x)[k], uc = (&Cv.x)[k], ud = (&Dv.x)[k];
                float alo = __builtin_bit_cast(float, ua << 16), ahi = __builtin_bit_cast(float, ua & 0xffff0000u);
                float blo = __builtin_bit_cast(float, ub << 16), bhi = __builtin_bit_cast(float, ub & 0xffff0000u);
                float clo = __builtin_bit_cast(float, uc << 16), chi = __builtin_bit_cast(float, uc & 0xffff0000u);
                float dlo = __builtin_bit_cast(float, ud << 16), dhi = __builtin_bit_cast(float, ud & 0xffff0000u);
                float vlo = g0 * alo + g1 * blo + g2 * clo + g3 * dlo;
                float vhi = g0 * ahi + g1 * bhi + g2 * chi + g3 * dhi;
                outw[k] = pack_bf2(vlo, vhi);
            }
            *(uint4*)&Vl[nxt][(unsigned)(c4g * 129 + posb) * 8] = make_uint4(outw[0], outw[1], outw[2], outw[3]);
        }
        __syncthreads();
    }

    // ---- epilogue: BN partial sums ----
    if (t < 256) { red0[t] = 0.f; red1[t] = 0.f; }
    __syncthreads();
#pragma unroll
    for (int i = 0; i < 4; i++) {
#pragma unroll
        for (int r = 0; r < 4; r++) {
            int o_loc = m0 + i * 16 + q * 4 + r;
            float s = 0.f, s2 = 0.f;
#pragma unroll
            for (int j = 0; j < 4; j++) { float v = acc[i][j][r]; s += v; s2 += v * v; }
            s  += __shfl_xor(s, 1);  s  += __shfl_xor(s, 2);  s  += __shfl_xor(s, 4);  s  += __shfl_xor(s, 8);
            s2 += __shfl_xor(s2, 1); s2 += __shfl_xor(s2, 2); s2 += __shfl_xor(s2, 4); s2 += __shfl_xor(s2, 8);
            if (l15 == 0) { atomicAdd(&red0[o_loc], s); atomicAdd(&red1[o_loc], s2); }
        }
    }
    __syncthreads();
    if (t < 256) {
        atomicAdd(&stats[t], red0[t]);
        atomicAdd(&stats[256 + t], red1[t]);
    }

    // ---- epilogue: direct C write (64B segments per 16-lane group; L2 write-combines) ----
    float* outb = out + ((size_t)b * O_) * HW_ + (size_t)h * W_;
#pragma unroll
    for (int i = 0; i < 4; i++)
#pragma unroll
        for (int j = 0; j < 4; j++) {
            int col = ph * 64 + j * 16 + l15;
#pragma unroll
            for (int r = 0; r < 4; r++) {
                int o = m0 + i * 16 + q * 4 + r;
                outb[(size_t)o * HW_ + col] = acc[i][j][r];
            }
        }
}

// ---------------- K4: BN stats finalize ----------------
__global__ void k_bnstats(float* __restrict__ stats,
                          const float* __restrict__ gamma,
                          const float* __restrict__ beta) {
    int t = threadIdx.x;  // 256
    float s = stats[t], s2 = stats[256 + t];
    float mean = s * (1.f / 65536.f);
    float var = s2 * (1.f / 65536.f) - mean * mean;
    float sc = gamma[t] * rsqrtf(var + 1e-5f);
    float sh = beta[t] - mean * sc;
    stats[512 + t] = sc;
    stats[768 + t] = sh;
}

// ---------------- K5: normalize + leaky ReLU (in-place on d_out) ----------------
__global__ __launch_bounds__(256) void k_apply(float* __restrict__ out,
                                               const float* __restrict__ stats) {
    int idx = blockIdx.x * 256 + threadIdx.x;
    int e = idx * 4;
    int o = (e >> 14) & 255;
    float sc = stats[512 + o], sh = stats[768 + o];
    float4 v = *(float4*)(out + e);
    v.x = v.x * sc + sh; v.x = (v.x >= 0.f) ? v.x : 0.1f * v.x;
    v.y = v.y * sc + sh; v.y = (v.y >= 0.f) ? v.y : 0.1f * v.y;
    v.z = v.z * sc + sh; v.z = (v.z >= 0.f) ? v.z : 0.1f * v.z;
    v.w = v.w * sc + sh; v.w = (v.w >= 0.f) ? v.w : 0.1f * v.w;
    *(float4*)(out + e) = v;
}

extern "C" void kernel_launch(void* const* d_in, const int* in_sizes, int n_in,
                              void* d_out, int out_size, void* d_ws, size_t ws_size,
                              hipStream_t stream) {
    const float* x      = (const float*)d_in[0];
    const float* p_w    = (const float*)d_in[1];
    const float* p_b    = (const float*)d_in[2];
    const float* w_conv = (const float*)d_in[3];
    const float* gamma  = (const float*)d_in[4];
    const float* beta   = (const float*)d_in[5];
    float* out = (float*)d_out;

    char* wsb = (char*)d_ws;
    unsigned short* xpad  = (unsigned short*)wsb;
    float*          offT  = (float*)(wsb + OFF_BYTE);
    unsigned short* wrepb = (unsigned short*)(wsb + WREPB_BYTE);
    float*          stats = (float*)(wsb + STATS_BYTE);
    short*          wofff = (short*)(wsb + WOFF_BYTE);

    hipMemsetAsync(xpad, 0, (size_t)XPAD_BYTES, stream);
    hipMemsetAsync(stats, 0, 4096, stream);

    k_transpose<<<dim3(W_ / 32, C_ / 32, B_ * H_), dim3(32, 8), 0, stream>>>(x, xpad);
    k_repack2<<<dim3(144), 256, 0, stream>>>(p_w, wofff);
    k_offconv<<<dim3(2, H_, B_), 256, 0, stream>>>(xpad, wofff, p_b, offT);
    k_repack<<<dim3((9 * C_ * O_ + 255) / 256), 256, 0, stream>>>(w_conv, wrepb);
    k_main<<<dim3(512), 512, 0, stream>>>(xpad, offT, wrepb, out, stats);
    k_bnstats<<<1, 256, 0, stream>>>(stats, gamma, beta);
    k_apply<<<dim3(16384), 256, 0, stream>>>(out, stats);
}